// Round 1
// baseline (326.243 us; speedup 1.0000x reference)
//
#include <hip/hip_runtime.h>
#include <math.h>

#define B_ 4
#define T_ 336
#define N_ 862
#define D_ 64
#define R_ 8
#define K_ 6
#define P_ 96

// workspace float offsets
#define OFF_SCAL 0        // [0]=g, [1]=s11, [2]=s12, [3]=s21, [4]=s22
#define OFF_CB   16       // 64
#define OFF_WG1  80       // 64
#define OFF_WG2  144      // 64
#define OFF_PC   208      // 96  (contiguous with PA: atomic target 192)
#define OFF_PA   304      // 96
#define OFF_XBAR 400      // 4*864
#define OFF_DINV 3856     // 864
#define OFF_AROW 4720     // 864
#define OFF_WGT  5584     // 3448*6 = 20688
#define OFF_IDX  26272    // 20688 (int)
#define OFF_P12  46960    // 336*192 = 64512
#define OFF_Y    111472   // 4*336*862 = 1158528
#define OFF_Y1   1270000  // 4*862*96 = 331008
#define OFF_ZS   1601008  // 862*384 = 331008

// K0: scalars, cb, Wg1, Wg2, zero Pc/Pa. one block of 64.
__global__ void k0_scalars(const float* __restrict__ We, const float* __restrict__ be,
                           const float* __restrict__ W1, const float* __restrict__ W2,
                           const float* __restrict__ gate, const float* __restrict__ Wgcn,
                           float* __restrict__ ws) {
  __shared__ float sc1[R_], sd1[R_], sc2[R_], sd2[R_];
  int tid = threadIdx.x;
  float g = 1.f / (1.f + expf(-gate[0]));
  if (tid < R_) {
    float a = 0.f, b = 0.f, c = 0.f, d = 0.f;
    for (int dd = 0; dd < D_; ++dd) {
      float w1 = W1[dd * R_ + tid], w2 = W2[dd * R_ + tid];
      a += We[dd] * w1; b += be[dd] * w1;
      c += We[dd] * w2; d += be[dd] * w2;
    }
    sc1[tid] = a; sd1[tid] = b; sc2[tid] = c; sd2[tid] = d;
  }
  __syncthreads();
  if (tid == 0) {
    float s11 = 0.f, s12 = 0.f, s21 = 0.f, s22 = 0.f;
    for (int r = 0; r < R_; ++r) {
      s11 += sc1[r] * sc2[r];
      s12 += sc1[r] * sd2[r];
      s21 += sd1[r] * sc2[r];
      s22 += sd1[r] * sd2[r];
    }
    ws[0] = g; ws[1] = s11; ws[2] = s12; ws[3] = s21; ws[4] = s22;
  }
  // cb, Wg1, Wg2 (tid = e in [0,64))
  float cb = (1.f + g) * be[tid];
  ws[OFF_CB + tid] = cb;
  float wg1 = 0.f, wg2 = 0.f;
  for (int dd = 0; dd < D_; ++dd) {
    float w = Wgcn[dd * D_ + tid];
    wg1 += We[dd] * w;
    wg2 += (1.f + g) * be[dd] * w;
  }
  ws[OFF_WG1 + tid] = wg1;
  ws[OFF_WG2 + tid] = wg2;
  // zero Pc/Pa (192 floats)
  ws[OFF_PC + tid] = 0.f;
  ws[OFF_PC + 64 + tid] = 0.f;
  ws[OFF_PC + 128 + tid] = 0.f;
}

// K1: xbar[b,n] = mean_t x[b,t,n]. grid(4,B) x 256
__global__ void k1_xbar(const float* __restrict__ x, float* __restrict__ ws) {
  int n = blockIdx.x * 256 + threadIdx.x;
  int b = blockIdx.y;
  if (n >= N_) return;
  const float* xp = x + (size_t)b * T_ * N_ + n;
  float s = 0.f;
  for (int t = 0; t < T_; ++t) s += xp[(size_t)t * N_];
  ws[OFF_XBAR + b * 864 + n] = s * (1.f / (float)T_);
}

// K1b: dinv[n]. grid 862 x 64
__global__ void k1b_dinv(const float* __restrict__ A, float* __restrict__ ws) {
  int n = blockIdx.x;
  int lane = threadIdx.x;
  const float* ap = A + (size_t)n * N_;
  float s = 0.f;
  for (int m = lane; m < N_; m += 64) s += ap[m];
  for (int off = 32; off; off >>= 1) s += __shfl_down(s, off);
  if (lane == 0) ws[OFF_DINV + n] = (s > 0.f) ? (1.f / sqrtf(s)) : 0.f;
}

// K1c: arow[n] = dinv[n]*sum_m A[n,m]*dinv[m]. grid 862 x 64
__global__ void k1c_arow(const float* __restrict__ A, float* __restrict__ ws) {
  int n = blockIdx.x;
  int lane = threadIdx.x;
  const float* ap = A + (size_t)n * N_;
  const float* dv = ws + OFF_DINV;
  float s = 0.f;
  for (int m = lane; m < N_; m += 64) s += ap[m] * dv[m];
  for (int off = 32; off; off >>= 1) s += __shfl_down(s, off);
  if (lane == 0) ws[OFF_AROW + n] = dv[n] * s;
}

// K2: top-K + softmax weights per row. grid(4,B) x 256
__global__ void k2_topk(float* __restrict__ ws) {
  __shared__ float sx[N_ + 2];
  int b = blockIdx.y;
  int tx = threadIdx.x;
  const float* xb = ws + OFF_XBAR + b * 864;
  for (int i = tx; i < N_; i += 256) sx[i] = xb[i];
  __syncthreads();
  int n = blockIdx.x * 256 + tx;
  if (n >= N_) return;
  float s11 = ws[1], s12 = ws[2], s21 = ws[3], s22 = ws[4];
  const float rsq = 0.3535533906f; // 1/sqrt(8)
  float xn = sx[n];
  float alpha = (xn * s11 + s21) * rsq;
  float beta  = (xn * s12 + s22) * rsq;
  float v[K_]; int id[K_];
#pragma unroll
  for (int j = 0; j < K_; ++j) { v[j] = -3.4e38f; id[j] = 0; }
  for (int m = 0; m < N_; ++m) {
    float l = fmaf(alpha, sx[m], beta);
    if (l > v[K_ - 1]) {
      v[K_ - 1] = l; id[K_ - 1] = m;
#pragma unroll
      for (int j = K_ - 1; j > 0; --j) {
        if (v[j] > v[j - 1]) {
          float tv = v[j]; v[j] = v[j - 1]; v[j - 1] = tv;
          int ti = id[j]; id[j] = id[j - 1]; id[j - 1] = ti;
        }
      }
    }
  }
  float mx = v[0];
  float w[K_]; float ssum = 0.f;
#pragma unroll
  for (int j = 0; j < K_; ++j) { w[j] = expf(v[j] - mx); ssum += w[j]; }
  float g = ws[0];
  float inv = g / ssum;  // fold sigmoid(gate) into weights
  int row = b * N_ + n;
  float* wp = ws + OFF_WGT + row * K_;
  int* ip = (int*)(ws + OFF_IDX) + row * K_;
#pragma unroll
  for (int j = 0; j < K_; ++j) { wp[j] = w[j] * inv; ip[j] = id[j]; }
}

// K3: y[b,t,n] = x[b,t,n] + sum_j wgt_j * x[b,t,idx_j]. grid B*T x 256
__global__ void k3_y(const float* __restrict__ x, float* __restrict__ ws) {
  __shared__ float sx[N_ + 2];
  int bt = blockIdx.x;
  int b = bt / T_, t = bt % T_;
  int tx = threadIdx.x;
  const float* xrow = x + (size_t)(b * T_ + t) * N_;
  for (int i = tx; i < N_; i += 256) sx[i] = xrow[i];
  __syncthreads();
  const float* wgt = ws + OFF_WGT;
  const int* idx = (const int*)(ws + OFF_IDX);
  float* yrow = ws + OFF_Y + (size_t)(b * T_ + t) * N_;
  for (int n = tx; n < N_; n += 256) {
    int row = b * N_ + n;
    const float* wp = wgt + row * K_;
    const int* ip = idx + row * K_;
    float acc = sx[n];
#pragma unroll
    for (int j = 0; j < K_; ++j) acc += wp[j] * sx[ip[j]];
    yrow[n] = acc;
  }
}

// K4: P12[t][c] projections of W_head; atomic partial Pc/Pa. grid T x 192
__global__ void k4_proj(const float* __restrict__ Whead, const float* __restrict__ We,
                        float* __restrict__ ws) {
  int t = blockIdx.x;
  int c = threadIdx.x;        // [0,192)
  int p = c % P_;
  int sel = c / P_;           // 0: We path (P1), 1: Wg1 path (P2)
  const float* cA = sel ? (ws + OFF_WG1) : We;
  const float* cB = sel ? (ws + OFF_WG2) : (ws + OFF_CB);
  const float* wrow = Whead + (size_t)t * D_ * P_ + p;
  float a = 0.f, bacc = 0.f;
#pragma unroll 8
  for (int e = 0; e < D_; ++e) {
    float w = wrow[(size_t)e * P_];
    a += cA[e] * w;
    bacc += cB[e] * w;
  }
  ws[OFF_P12 + t * 192 + c] = a;
  atomicAdd(&ws[OFF_PC + c], bacc);  // Pc for c<96, Pa for c>=96
}

// K5: Y1[b,n,p] = sum_t y[b,t,n]*P1[t,p]; Zs[n, b*96+p] = dinv[n]*sum_t y*P2.
// grid(431,B) x 384  (2 n per block, 192 c per n)
__global__ void k5_gemm(float* __restrict__ ws) {
  int b = blockIdx.y;
  int tx = threadIdx.x;
  int nl = tx / 192;
  int c = tx % 192;
  int n = blockIdx.x * 2 + nl;
  const float* yb = ws + OFF_Y + (size_t)b * T_ * N_ + n;
  const float* Pp = ws + OFF_P12 + c;
  float acc = 0.f;
#pragma unroll 4
  for (int t = 0; t < T_; ++t) acc += yb[(size_t)t * N_] * Pp[t * 192];
  if (c < P_) {
    ws[OFF_Y1 + ((size_t)b * N_ + n) * P_ + c] = acc;
  } else {
    float dv = ws[OFF_DINV + n];
    ws[OFF_ZS + (size_t)n * 384 + b * P_ + (c - P_)] = dv * acc;
  }
}

// K6: S = A_prior @ Zs (wave-uniform zero-skip), final assembly. grid N_ x 384
__global__ void k6_final(const float* __restrict__ A, const float* __restrict__ bhead,
                         const float* __restrict__ ggcn, const float* __restrict__ ws,
                         float* __restrict__ out) {
  __shared__ float sa[N_ + 2];
  int n = blockIdx.x;
  int tx = threadIdx.x;  // = b*96+p, [0,384)
  const float* arow_g = A + (size_t)n * N_;
  for (int i = tx; i < N_; i += 384) sa[i] = arow_g[i];
  __syncthreads();
  const float* Zs = ws + OFF_ZS;
  float acc = 0.f;
  for (int m = 0; m < N_; ++m) {
    float a = sa[m];
    unsigned ra = __builtin_amdgcn_readfirstlane(__float_as_uint(a));
    if ((ra << 1) != 0u) acc += a * Zs[(size_t)m * 384 + tx];
  }
  int b = tx / P_, p = tx % P_;
  float gg = ggcn[0];
  float val = ws[OFF_Y1 + ((size_t)b * N_ + n) * P_ + p]
            + gg * (ws[OFF_DINV + n] * acc + ws[OFF_AROW + n] * ws[OFF_PA + p])
            + ws[OFF_PC + p] + bhead[p];
  out[(size_t)tx * N_ + n] = val;
}

extern "C" void kernel_launch(void* const* d_in, const int* in_sizes, int n_in,
                              void* d_out, int out_size, void* d_ws, size_t ws_size,
                              hipStream_t stream) {
  const float* x     = (const float*)d_in[0];
  const float* We    = (const float*)d_in[1];
  const float* be    = (const float*)d_in[2];
  const float* W1    = (const float*)d_in[3];
  const float* W2    = (const float*)d_in[4];
  const float* gate  = (const float*)d_in[5];
  const float* A     = (const float*)d_in[6];
  const float* Wgcn  = (const float*)d_in[7];
  const float* ggcn  = (const float*)d_in[8];
  const float* Whead = (const float*)d_in[9];
  const float* bhead = (const float*)d_in[10];
  float* ws = (float*)d_ws;
  float* out = (float*)d_out;

  k0_scalars<<<1, 64, 0, stream>>>(We, be, W1, W2, gate, Wgcn, ws);
  k1_xbar<<<dim3(4, B_), 256, 0, stream>>>(x, ws);
  k1b_dinv<<<N_, 64, 0, stream>>>(A, ws);
  k1c_arow<<<N_, 64, 0, stream>>>(A, ws);
  k2_topk<<<dim3(4, B_), 256, 0, stream>>>(ws);
  k3_y<<<B_ * T_, 256, 0, stream>>>(x, ws);
  k4_proj<<<T_, 192, 0, stream>>>(Whead, We, ws);
  k5_gemm<<<dim3(431, B_), 384, 0, stream>>>(ws);
  k6_final<<<N_, 384, 0, stream>>>(A, bhead, ggcn, ws, out);
}

// Round 2
// 208.201 us; speedup vs baseline: 1.5670x; 1.5670x over previous
//
#include <hip/hip_runtime.h>
#include <math.h>

#define B_ 4
#define T_ 336
#define N_ 862
#define D_ 64
#define R_ 8
#define K_ 6
#define P_ 96

// workspace float offsets
#define OFF_SCAL 0        // [0]=g, [1]=s11, [2]=s12, [3]=s21, [4]=s22
#define OFF_CB   16       // 64
#define OFF_WG1  80       // 64
#define OFF_WG2  144      // 64
#define OFF_PC   208      // 96 (contiguous with PA: atomic target 192)
#define OFF_PA   304      // 96
#define OFF_XBAR 400      // 4*864 (t-sums, atomically accumulated)
#define OFF_DINV 3856     // 864
#define OFF_AROW 4720     // 864
#define OFF_WGT  5584     // 3448*6
#define OFF_IDX  26272    // 3448*6 (int)
#define OFF_P12  46960    // 336*192
#define OFF_XP   111472   // 4*862*192 = 662016
#define OFF_Y1   773488   // 4*862*96 = 331008
#define OFF_ZS   1104496  // 862*384 = 331008 (end 1435504 floats)

// K0: scalars, cb, Wg1, Wg2, zero Pc/Pa and xbar. one block of 64.
__global__ void k0_scalars(const float* __restrict__ We, const float* __restrict__ be,
                           const float* __restrict__ W1, const float* __restrict__ W2,
                           const float* __restrict__ gate, const float* __restrict__ Wgcn,
                           float* __restrict__ ws) {
  __shared__ float sc1[R_], sd1[R_], sc2[R_], sd2[R_];
  int tid = threadIdx.x;
  float g = 1.f / (1.f + expf(-gate[0]));
  if (tid < R_) {
    float a = 0.f, b = 0.f, c = 0.f, d = 0.f;
    for (int dd = 0; dd < D_; ++dd) {
      float w1 = W1[dd * R_ + tid], w2 = W2[dd * R_ + tid];
      a += We[dd] * w1; b += be[dd] * w1;
      c += We[dd] * w2; d += be[dd] * w2;
    }
    sc1[tid] = a; sd1[tid] = b; sc2[tid] = c; sd2[tid] = d;
  }
  __syncthreads();
  if (tid == 0) {
    float s11 = 0.f, s12 = 0.f, s21 = 0.f, s22 = 0.f;
    for (int r = 0; r < R_; ++r) {
      s11 += sc1[r] * sc2[r];
      s12 += sc1[r] * sd2[r];
      s21 += sd1[r] * sc2[r];
      s22 += sd1[r] * sd2[r];
    }
    ws[0] = g; ws[1] = s11; ws[2] = s12; ws[3] = s21; ws[4] = s22;
  }
  float cb = (1.f + g) * be[tid];
  ws[OFF_CB + tid] = cb;
  float wg1 = 0.f, wg2 = 0.f;
  for (int dd = 0; dd < D_; ++dd) {
    float w = Wgcn[dd * D_ + tid];
    wg1 += We[dd] * w;
    wg2 += (1.f + g) * be[dd] * w;
  }
  ws[OFF_WG1 + tid] = wg1;
  ws[OFF_WG2 + tid] = wg2;
  ws[OFF_PC + tid] = 0.f;
  ws[OFF_PC + 64 + tid] = 0.f;
  ws[OFF_PC + 128 + tid] = 0.f;
  for (int i = tid; i < 4 * 864; i += 64) ws[OFF_XBAR + i] = 0.f;
}

// K1: t-sums of x, t-split with atomicAdd. grid(14,B,6) x 256
__global__ void k1_sum(const float* __restrict__ x, float* __restrict__ ws) {
  __shared__ float part[256];
  int nl = threadIdx.x & 63, tl = threadIdx.x >> 6;
  int n = blockIdx.x * 64 + nl;
  int b = blockIdx.y;
  int t0 = blockIdx.z * 56;
  float s = 0.f;
  if (n < N_) {
    const float* xp = x + (size_t)(b * T_) * N_ + n;
#pragma unroll 7
    for (int si = 0; si < 14; ++si) {
      int t = t0 + tl + si * 4;
      s += xp[(size_t)t * N_];
    }
  }
  part[threadIdx.x] = s;
  __syncthreads();
  if (tl == 0 && n < N_) {
    float tot = part[nl] + part[64 + nl] + part[128 + nl] + part[192 + nl];
    atomicAdd(&ws[OFF_XBAR + b * 864 + n], tot);
  }
}

// K1b: dinv[n]. grid 862 x 64
__global__ void k1b_dinv(const float* __restrict__ A, float* __restrict__ ws) {
  int n = blockIdx.x;
  int lane = threadIdx.x;
  const float* ap = A + (size_t)n * N_;
  float s = 0.f;
  for (int m = lane; m < N_; m += 64) s += ap[m];
  for (int off = 32; off; off >>= 1) s += __shfl_down(s, off);
  if (lane == 0) ws[OFF_DINV + n] = (s > 0.f) ? (1.f / sqrtf(s)) : 0.f;
}

// K1c: arow[n] = dinv[n]*sum_m A[n,m]*dinv[m]. grid 862 x 64
__global__ void k1c_arow(const float* __restrict__ A, float* __restrict__ ws) {
  int n = blockIdx.x;
  int lane = threadIdx.x;
  const float* ap = A + (size_t)n * N_;
  const float* dv = ws + OFF_DINV;
  float s = 0.f;
  for (int m = lane; m < N_; m += 64) s += ap[m] * dv[m];
  for (int off = 32; off; off >>= 1) s += __shfl_down(s, off);
  if (lane == 0) ws[OFF_AROW + n] = dv[n] * s;
}

// K2: per-batch top-6/bottom-6 of xbar, then per-n weights. grid B x 256.
// logit[n,m] = alpha_n * xbar[m] + beta_n is affine in xbar[m], so the
// row top-K is the global top-6 (alpha>=0) or bottom-6 (alpha<0).
__global__ void k2_topk(float* __restrict__ ws) {
  __shared__ float sx[864];
  __shared__ float work[864];
  __shared__ float wv[4];
  __shared__ int wi[4];
  __shared__ float selv[12];
  __shared__ int seli[12];
  int b = blockIdx.x;
  int tid = threadIdx.x;
  const float invT = 1.f / (float)T_;
  for (int i = tid; i < 864; i += 256) {
    float v = (i < N_) ? ws[OFF_XBAR + b * 864 + i] * invT : 0.f;
    sx[i] = v;
    work[i] = (i < N_) ? v : -3.4e38f;
  }
  __syncthreads();
  int lane = tid & 63, wgrp = tid >> 6;
  for (int r = 0; r < K_; ++r) {
    float bv = -3.4e38f; int bi = 0;
    for (int i = tid; i < N_; i += 256) {
      float v = work[i];
      if (v > bv) { bv = v; bi = i; }
    }
    for (int off = 32; off; off >>= 1) {
      float ov = __shfl_down(bv, off);
      int oi = __shfl_down(bi, off);
      if (ov > bv) { bv = ov; bi = oi; }
    }
    if (lane == 0) { wv[wgrp] = bv; wi[wgrp] = bi; }
    __syncthreads();
    if (tid == 0) {
      float mv = wv[0]; int mi = wi[0];
      for (int q = 1; q < 4; ++q) if (wv[q] > mv) { mv = wv[q]; mi = wi[q]; }
      selv[r] = mv; seli[r] = mi;
      work[mi] = -3.4e38f;
    }
    __syncthreads();
  }
  for (int i = tid; i < 864; i += 256) work[i] = (i < N_) ? sx[i] : 3.4e38f;
  __syncthreads();
  for (int r = 0; r < K_; ++r) {
    float bv = 3.4e38f; int bi = 0;
    for (int i = tid; i < N_; i += 256) {
      float v = work[i];
      if (v < bv) { bv = v; bi = i; }
    }
    for (int off = 32; off; off >>= 1) {
      float ov = __shfl_down(bv, off);
      int oi = __shfl_down(bi, off);
      if (ov < bv) { bv = ov; bi = oi; }
    }
    if (lane == 0) { wv[wgrp] = bv; wi[wgrp] = bi; }
    __syncthreads();
    if (tid == 0) {
      float mv = wv[0]; int mi = wi[0];
      for (int q = 1; q < 4; ++q) if (wv[q] < mv) { mv = wv[q]; mi = wi[q]; }
      selv[6 + r] = mv; seli[6 + r] = mi;
      work[mi] = 3.4e38f;
    }
    __syncthreads();
  }
  float s11 = ws[1], s12 = ws[2], s21 = ws[3], s22 = ws[4], g = ws[0];
  const float rsq = 0.3535533906f;
  for (int n = tid; n < N_; n += 256) {
    float xn = sx[n];
    float alpha = (xn * s11 + s21) * rsq;
    float beta  = (xn * s12 + s22) * rsq;
    int base = (alpha >= 0.f) ? 0 : 6;
    float l[K_]; float mx = -3.4e38f;
#pragma unroll
    for (int j = 0; j < K_; ++j) { l[j] = alpha * selv[base + j] + beta; mx = fmaxf(mx, l[j]); }
    float e[K_]; float ss = 0.f;
#pragma unroll
    for (int j = 0; j < K_; ++j) { e[j] = expf(l[j] - mx); ss += e[j]; }
    float sc = g / ss;
    int row = b * N_ + n;
    float* wp = ws + OFF_WGT + row * K_;
    int* ip = (int*)(ws + OFF_IDX) + row * K_;
#pragma unroll
    for (int j = 0; j < K_; ++j) { wp[j] = e[j] * sc; ip[j] = seli[base + j]; }
  }
}

// K4: P12[t][c] projections of W_head; atomic partial Pc/Pa. grid T x 192
__global__ void k4_proj(const float* __restrict__ Whead, const float* __restrict__ We,
                        float* __restrict__ ws) {
  int t = blockIdx.x;
  int c = threadIdx.x;
  int p = c % P_;
  int sel = c / P_;
  const float* cA = sel ? (ws + OFF_WG1) : We;
  const float* cB = sel ? (ws + OFF_WG2) : (ws + OFF_CB);
  const float* wrow = Whead + (size_t)t * D_ * P_ + p;
  float a = 0.f, bacc = 0.f;
#pragma unroll 8
  for (int e = 0; e < D_; ++e) {
    float w = wrow[(size_t)e * P_];
    a += cA[e] * w;
    bacc += cB[e] * w;
  }
  ws[OFF_P12 + t * 192 + c] = a;
  atomicAdd(&ws[OFF_PC + c], bacc);
}

// K5: Xp[b,n,c] = sum_t x[b,t,n] * P12[t,c]. Tiled GEMM.
// grid(54,B) x 256. Block tile 16n x 192c, BK=48 (336=7*48).
// Thread: cg=tid&63 -> c0=cg*3 ; ng=tid>>6 -> 4 n via float4 broadcast.
__global__ __launch_bounds__(256) void k5_gemm(const float* __restrict__ x,
                                               float* __restrict__ ws) {
  __shared__ float xs[48 * 16];
  __shared__ float ps[48 * 192];
  int b = blockIdx.y;
  int n0 = blockIdx.x * 16;
  int tid = threadIdx.x;
  int cg = tid & 63, ng = tid >> 6;
  int c0 = cg * 3;
  const float* P = ws + OFF_P12;
  float a00 = 0.f, a01 = 0.f, a02 = 0.f;
  float a10 = 0.f, a11 = 0.f, a12 = 0.f;
  float a20 = 0.f, a21 = 0.f, a22 = 0.f;
  float a30 = 0.f, a31 = 0.f, a32 = 0.f;
  for (int kc = 0; kc < 7; ++kc) {
    int t0 = kc * 48;
#pragma unroll
    for (int s = 0; s < 3; ++s) {
      int i = tid + s * 256;
      int row = i >> 4, col = i & 15;
      int nn = n0 + col; if (nn > N_ - 1) nn = N_ - 1;
      xs[i] = x[(size_t)(b * T_ + t0 + row) * N_ + nn];
    }
#pragma unroll
    for (int s = 0; s < 9; ++s) {
      int i4 = tid + s * 256;
      int row = i4 / 48, col4 = i4 - row * 48;
      float4 v = *(const float4*)(P + (size_t)(t0 + row) * 192 + col4 * 4);
      *(float4*)(ps + row * 192 + col4 * 4) = v;
    }
    __syncthreads();
#pragma unroll 8
    for (int kk = 0; kk < 48; ++kk) {
      float4 xv = *(const float4*)(xs + kk * 16 + ng * 4);
      float p0 = ps[kk * 192 + c0];
      float p1 = ps[kk * 192 + c0 + 1];
      float p2 = ps[kk * 192 + c0 + 2];
      a00 = fmaf(xv.x, p0, a00); a01 = fmaf(xv.x, p1, a01); a02 = fmaf(xv.x, p2, a02);
      a10 = fmaf(xv.y, p0, a10); a11 = fmaf(xv.y, p1, a11); a12 = fmaf(xv.y, p2, a12);
      a20 = fmaf(xv.z, p0, a20); a21 = fmaf(xv.z, p1, a21); a22 = fmaf(xv.z, p2, a22);
      a30 = fmaf(xv.w, p0, a30); a31 = fmaf(xv.w, p1, a31); a32 = fmaf(xv.w, p2, a32);
    }
    __syncthreads();
  }
  float accs[4][3] = {{a00,a01,a02},{a10,a11,a12},{a20,a21,a22},{a30,a31,a32}};
#pragma unroll
  for (int i = 0; i < 4; ++i) {
    int n = n0 + ng * 4 + i;
    if (n < N_) {
      float* op = ws + OFF_XP + ((size_t)(b * N_ + n)) * 192 + c0;
      op[0] = accs[i][0]; op[1] = accs[i][1]; op[2] = accs[i][2];
    }
  }
}

// K5b: mix commuted past t-contraction.
// Y1[b,n,p] = Xp1[n] + sum_j w_j Xp1[idx_j]; Zs from Xp2 half. grid(862,B) x 192
__global__ void k5b_mix(float* __restrict__ ws) {
  int n = blockIdx.x, b = blockIdx.y, c = threadIdx.x;
  int row = b * N_ + n;
  const float* wp = ws + OFF_WGT + row * K_;
  const int* ip = (const int*)(ws + OFF_IDX) + row * K_;
  const float* Xp = ws + OFF_XP;
  float acc = Xp[(size_t)row * 192 + c];
#pragma unroll
  for (int j = 0; j < K_; ++j)
    acc += wp[j] * Xp[((size_t)(b * N_ + ip[j])) * 192 + c];
  if (c < P_) ws[OFF_Y1 + (size_t)row * P_ + c] = acc;
  else ws[OFF_ZS + (size_t)n * 384 + b * P_ + (c - P_)] = ws[OFF_DINV + n] * acc;
}

// K6: S = A_prior @ Zs (wave-uniform zero-skip), final assembly. grid N_ x 384
__global__ void k6_final(const float* __restrict__ A, const float* __restrict__ bhead,
                         const float* __restrict__ ggcn, const float* __restrict__ ws,
                         float* __restrict__ out) {
  __shared__ float sa[N_ + 2];
  int n = blockIdx.x;
  int tx = threadIdx.x;
  const float* arow_g = A + (size_t)n * N_;
  for (int i = tx; i < N_; i += 384) sa[i] = arow_g[i];
  __syncthreads();
  const float* Zs = ws + OFF_ZS;
  float acc = 0.f;
  for (int m = 0; m < N_; ++m) {
    float a = sa[m];
    unsigned ra = __builtin_amdgcn_readfirstlane(__float_as_uint(a));
    if ((ra << 1) != 0u) acc += a * Zs[(size_t)m * 384 + tx];
  }
  int b = tx / P_, p = tx % P_;
  float gg = ggcn[0];
  float val = ws[OFF_Y1 + ((size_t)b * N_ + n) * P_ + p]
            + gg * (ws[OFF_DINV + n] * acc + ws[OFF_AROW + n] * ws[OFF_PA + p])
            + ws[OFF_PC + p] + bhead[p];
  out[(size_t)tx * N_ + n] = val;
}

extern "C" void kernel_launch(void* const* d_in, const int* in_sizes, int n_in,
                              void* d_out, int out_size, void* d_ws, size_t ws_size,
                              hipStream_t stream) {
  const float* x     = (const float*)d_in[0];
  const float* We    = (const float*)d_in[1];
  const float* be    = (const float*)d_in[2];
  const float* W1    = (const float*)d_in[3];
  const float* W2    = (const float*)d_in[4];
  const float* gate  = (const float*)d_in[5];
  const float* A     = (const float*)d_in[6];
  const float* Wgcn  = (const float*)d_in[7];
  const float* ggcn  = (const float*)d_in[8];
  const float* Whead = (const float*)d_in[9];
  const float* bhead = (const float*)d_in[10];
  float* ws = (float*)d_ws;
  float* out = (float*)d_out;

  k0_scalars<<<1, 64, 0, stream>>>(We, be, W1, W2, gate, Wgcn, ws);
  k1_sum<<<dim3(14, B_, 6), 256, 0, stream>>>(x, ws);
  k1b_dinv<<<N_, 64, 0, stream>>>(A, ws);
  k1c_arow<<<N_, 64, 0, stream>>>(A, ws);
  k2_topk<<<B_, 256, 0, stream>>>(ws);
  k4_proj<<<T_, 192, 0, stream>>>(Whead, We, ws);
  k5_gemm<<<dim3(54, B_), 256, 0, stream>>>(x, ws);
  k5b_mix<<<dim3(N_, B_), 192, 0, stream>>>(ws);
  k6_final<<<N_, 384, 0, stream>>>(A, bhead, ggcn, ws, out);
}

// Round 3
// 163.289 us; speedup vs baseline: 1.9980x; 1.2750x over previous
//
#include <hip/hip_runtime.h>
#include <math.h>

#define B_ 4
#define T_ 336
#define N_ 862
#define D_ 64
#define R_ 8
#define K_ 6
#define P_ 96
#define NR 896   // padded n-stride
#define CAP 32   // CSR cap per row

// workspace float offsets
#define OFF_SCAL 0        // [0]=g, [1]=s11, [2]=s12, [3]=s21, [4]=s22
#define OFF_CB   16       // 64
#define OFF_WG1  80       // 64
#define OFF_WG2  144      // 64
#define OFF_PC   208      // 96 (contiguous with PA: atomic target 192)
#define OFF_PA   304      // 96
#define OFF_XBAR 400      // 4*864 (raw t-sums, written by k5)
#define OFF_DINV 3856     // 864
#define OFF_AROW 4720     // 864
#define OFF_WGT  5584     // 3448*6
#define OFF_IDX  26272    // 3448*6 (int)
#define OFF_CNT  46960    // 864 (int)
#define OFF_CSRV 47824    // 32*864 (j-major: [j*864+n])
#define OFF_CSRI 75472    // 32*864 (int, j-major)
#define OFF_P12  103120   // 336*192
#define OFF_XPT  167632   // 4*192*896 = 688128
#define OFF_Y1T  855760   // 4*96*896 = 344064
#define OFF_ZST  1199824  // 4*96*896 = 344064 (end 1543888 floats = 6.18 MB)

// K0: scalars, cb, Wg1, Wg2, zero Pc/Pa. one block of 64.
__global__ void k0_scalars(const float* __restrict__ We, const float* __restrict__ be,
                           const float* __restrict__ W1, const float* __restrict__ W2,
                           const float* __restrict__ gate, const float* __restrict__ Wgcn,
                           float* __restrict__ ws) {
  __shared__ float sc1[R_], sd1[R_], sc2[R_], sd2[R_];
  int tid = threadIdx.x;
  float g = 1.f / (1.f + expf(-gate[0]));
  if (tid < R_) {
    float a = 0.f, b = 0.f, c = 0.f, d = 0.f;
    for (int dd = 0; dd < D_; ++dd) {
      float w1 = W1[dd * R_ + tid], w2 = W2[dd * R_ + tid];
      a += We[dd] * w1; b += be[dd] * w1;
      c += We[dd] * w2; d += be[dd] * w2;
    }
    sc1[tid] = a; sd1[tid] = b; sc2[tid] = c; sd2[tid] = d;
  }
  __syncthreads();
  if (tid == 0) {
    float s11 = 0.f, s12 = 0.f, s21 = 0.f, s22 = 0.f;
    for (int r = 0; r < R_; ++r) {
      s11 += sc1[r] * sc2[r];
      s12 += sc1[r] * sd2[r];
      s21 += sd1[r] * sc2[r];
      s22 += sd1[r] * sd2[r];
    }
    ws[0] = g; ws[1] = s11; ws[2] = s12; ws[3] = s21; ws[4] = s22;
  }
  ws[OFF_CB + tid] = (1.f + g) * be[tid];
  float wg1 = 0.f, wg2 = 0.f;
  for (int dd = 0; dd < D_; ++dd) {
    float w = Wgcn[dd * D_ + tid];
    wg1 += We[dd] * w;
    wg2 += (1.f + g) * be[dd] * w;
  }
  ws[OFF_WG1 + tid] = wg1;
  ws[OFF_WG2 + tid] = wg2;
  ws[OFF_PC + tid] = 0.f;
  ws[OFF_PC + 64 + tid] = 0.f;
  ws[OFF_PC + 128 + tid] = 0.f;
}

// K1b: dinv[n]. grid 862 x 64
__global__ void k1b_dinv(const float* __restrict__ A, float* __restrict__ ws) {
  int n = blockIdx.x;
  int lane = threadIdx.x;
  const float* ap = A + (size_t)n * N_;
  float s = 0.f;
  for (int m = lane; m < N_; m += 64) s += ap[m];
  for (int off = 32; off; off >>= 1) s += __shfl_down(s, off);
  if (lane == 0) ws[OFF_DINV + n] = (s > 0.f) ? (1.f / sqrtf(s)) : 0.f;
}

// K_csr: arow[n] + CSR of A row (ballot compaction, j-major). grid 862 x 64
__global__ void k_csr(const float* __restrict__ A, float* __restrict__ ws) {
  int n = blockIdx.x;
  int lane = threadIdx.x;
  const float* ap = A + (size_t)n * N_;
  const float* dv = ws + OFF_DINV;
  float* vout = ws + OFF_CSRV;
  int* iout = (int*)(ws + OFF_CSRI);
  float s = 0.f;
  int total = 0;
  for (int base = 0; base < N_; base += 64) {
    int m = base + lane;
    float a = (m < N_) ? ap[m] : 0.f;
    if (m < N_) s += a * dv[m];
    bool nz = (a != 0.f);
    unsigned long long mask = __ballot(nz);
    int pos = __popcll(mask & ((1ull << lane) - 1ull));
    if (nz) {
      int slot = total + pos;
      if (slot < CAP) { vout[slot * 864 + n] = a; iout[slot * 864 + n] = m; }
    }
    total += __popcll(mask);
  }
  for (int off = 32; off; off >>= 1) s += __shfl_down(s, off);
  if (lane == 0) {
    ws[OFF_AROW + n] = dv[n] * s;
    ((int*)(ws + OFF_CNT))[n] = (total <= CAP) ? total : -1;
  }
}

// K4: P12[t][c] projections of W_head; block-local accumulation then atomics.
// grid 48 x 192, 7 t per block.
__global__ void k4_proj(const float* __restrict__ Whead, const float* __restrict__ We,
                        float* __restrict__ ws) {
  int c = threadIdx.x;
  int p = c % P_;
  int sel = c / P_;
  const float* cA = sel ? (ws + OFF_WG1) : We;
  const float* cB = sel ? (ws + OFF_WG2) : (ws + OFF_CB);
  float bacc = 0.f;
  for (int tt = 0; tt < 7; ++tt) {
    int t = blockIdx.x * 7 + tt;
    const float* wrow = Whead + (size_t)t * D_ * P_ + p;
    float a = 0.f;
#pragma unroll 8
    for (int e = 0; e < D_; ++e) {
      float w = wrow[(size_t)e * P_];
      a += cA[e] * w;
      bacc += cB[e] * w;
    }
    ws[OFF_P12 + t * 192 + c] = a;
  }
  atomicAdd(&ws[OFF_PC + c], bacc);
}

// K5: XpT[(b*192+c)*NR + n] = sum_t x[b,t,n] * P12[t,c]; also xbar t-sums.
// grid(54,B) x 192. Block tile 16n x 192c, BK=48. Thread: 4c x 4n.
__global__ __launch_bounds__(192) void k5_gemm(const float* __restrict__ x,
                                               float* __restrict__ ws) {
  __shared__ float xs[48 * 16];
  __shared__ float ps[48 * 192];
  int b = blockIdx.y;
  int n0 = blockIdx.x * 16;
  int tid = threadIdx.x;
  int cq = tid % 48, nq = tid / 48;   // nq in [0,4)
  int c0 = cq * 4;
  const float* P = ws + OFF_P12;
  float acc[4][4];
#pragma unroll
  for (int i = 0; i < 4; ++i)
#pragma unroll
    for (int j = 0; j < 4; ++j) acc[i][j] = 0.f;
  float colsum = 0.f;
  int xrow = tid >> 2, xcol4 = tid & 3;
  for (int kc = 0; kc < 7; ++kc) {
    int t0 = kc * 48;
    {
      const float* xr = x + (size_t)(b * T_ + t0 + xrow) * N_;
      if (n0 + 15 < N_) {
        *(float4*)(xs + xrow * 16 + xcol4 * 4) = *(const float4*)(xr + n0 + xcol4 * 4);
      } else {
        float* dst = xs + xrow * 16 + xcol4 * 4;
#pragma unroll
        for (int q = 0; q < 4; ++q) {
          int nn = n0 + xcol4 * 4 + q; if (nn > N_ - 1) nn = N_ - 1;
          dst[q] = xr[nn];
        }
      }
    }
#pragma unroll
    for (int sIdx = 0; sIdx < 12; ++sIdx) {
      int i4 = tid + sIdx * 192;
      int row = i4 / 48, col4 = i4 % 48;
      *(float4*)(ps + row * 192 + col4 * 4) =
          *(const float4*)(P + (size_t)(t0 + row) * 192 + col4 * 4);
    }
    __syncthreads();
    if (tid < 16) {
#pragma unroll 8
      for (int kk = 0; kk < 48; ++kk) colsum += xs[kk * 16 + tid];
    }
#pragma unroll 4
    for (int kk = 0; kk < 48; ++kk) {
      float4 xv = *(const float4*)(xs + kk * 16 + nq * 4);
      float4 pv = *(const float4*)(ps + kk * 192 + c0);
      acc[0][0] = fmaf(pv.x, xv.x, acc[0][0]); acc[0][1] = fmaf(pv.x, xv.y, acc[0][1]);
      acc[0][2] = fmaf(pv.x, xv.z, acc[0][2]); acc[0][3] = fmaf(pv.x, xv.w, acc[0][3]);
      acc[1][0] = fmaf(pv.y, xv.x, acc[1][0]); acc[1][1] = fmaf(pv.y, xv.y, acc[1][1]);
      acc[1][2] = fmaf(pv.y, xv.z, acc[1][2]); acc[1][3] = fmaf(pv.y, xv.w, acc[1][3]);
      acc[2][0] = fmaf(pv.z, xv.x, acc[2][0]); acc[2][1] = fmaf(pv.z, xv.y, acc[2][1]);
      acc[2][2] = fmaf(pv.z, xv.z, acc[2][2]); acc[2][3] = fmaf(pv.z, xv.w, acc[2][3]);
      acc[3][0] = fmaf(pv.w, xv.x, acc[3][0]); acc[3][1] = fmaf(pv.w, xv.y, acc[3][1]);
      acc[3][2] = fmaf(pv.w, xv.z, acc[3][2]); acc[3][3] = fmaf(pv.w, xv.w, acc[3][3]);
    }
    __syncthreads();
  }
#pragma unroll
  for (int cc = 0; cc < 4; ++cc) {
    float4 v;
    v.x = acc[cc][0]; v.y = acc[cc][1]; v.z = acc[cc][2]; v.w = acc[cc][3];
    *(float4*)(ws + OFF_XPT + ((size_t)(b * 192 + c0 + cc)) * NR + n0 + nq * 4) = v;
  }
  if (tid < 16 && n0 + tid < N_) ws[OFF_XBAR + b * 864 + n0 + tid] = colsum;
}

// K2: per-batch top-6/bottom-6 of xbar, then per-n weights. grid B x 256.
__global__ void k2_topk(float* __restrict__ ws) {
  __shared__ float sx[864];
  __shared__ float work[864];
  __shared__ float wv[4];
  __shared__ int wi[4];
  __shared__ float selv[12];
  __shared__ int seli[12];
  int b = blockIdx.x;
  int tid = threadIdx.x;
  const float invT = 1.f / (float)T_;
  for (int i = tid; i < 864; i += 256) {
    float v = (i < N_) ? ws[OFF_XBAR + b * 864 + i] * invT : 0.f;
    sx[i] = v;
    work[i] = (i < N_) ? v : -3.4e38f;
  }
  __syncthreads();
  int lane = tid & 63, wgrp = tid >> 6;
  for (int r = 0; r < K_; ++r) {
    float bv = -3.4e38f; int bi = 0;
    for (int i = tid; i < N_; i += 256) {
      float v = work[i];
      if (v > bv) { bv = v; bi = i; }
    }
    for (int off = 32; off; off >>= 1) {
      float ov = __shfl_down(bv, off);
      int oi = __shfl_down(bi, off);
      if (ov > bv) { bv = ov; bi = oi; }
    }
    if (lane == 0) { wv[wgrp] = bv; wi[wgrp] = bi; }
    __syncthreads();
    if (tid == 0) {
      float mv = wv[0]; int mi = wi[0];
      for (int q = 1; q < 4; ++q) if (wv[q] > mv) { mv = wv[q]; mi = wi[q]; }
      selv[r] = mv; seli[r] = mi;
      work[mi] = -3.4e38f;
    }
    __syncthreads();
  }
  for (int i = tid; i < 864; i += 256) work[i] = (i < N_) ? sx[i] : 3.4e38f;
  __syncthreads();
  for (int r = 0; r < K_; ++r) {
    float bv = 3.4e38f; int bi = 0;
    for (int i = tid; i < N_; i += 256) {
      float v = work[i];
      if (v < bv) { bv = v; bi = i; }
    }
    for (int off = 32; off; off >>= 1) {
      float ov = __shfl_down(bv, off);
      int oi = __shfl_down(bi, off);
      if (ov < bv) { bv = ov; bi = oi; }
    }
    if (lane == 0) { wv[wgrp] = bv; wi[wgrp] = bi; }
    __syncthreads();
    if (tid == 0) {
      float mv = wv[0]; int mi = wi[0];
      for (int q = 1; q < 4; ++q) if (wv[q] < mv) { mv = wv[q]; mi = wi[q]; }
      selv[6 + r] = mv; seli[6 + r] = mi;
      work[mi] = 3.4e38f;
    }
    __syncthreads();
  }
  float s11 = ws[1], s12 = ws[2], s21 = ws[3], s22 = ws[4], g = ws[0];
  const float rsq = 0.3535533906f;
  for (int n = tid; n < N_; n += 256) {
    float xn = sx[n];
    float alpha = (xn * s11 + s21) * rsq;
    float beta  = (xn * s12 + s22) * rsq;
    int base = (alpha >= 0.f) ? 0 : 6;
    float l[K_]; float mx = -3.4e38f;
#pragma unroll
    for (int j = 0; j < K_; ++j) { l[j] = alpha * selv[base + j] + beta; mx = fmaxf(mx, l[j]); }
    float e[K_]; float ss = 0.f;
#pragma unroll
    for (int j = 0; j < K_; ++j) { e[j] = expf(l[j] - mx); ss += e[j]; }
    float sc = g / ss;
    int row = b * N_ + n;
    float* wp = ws + OFF_WGT + row * K_;
    int* ip = (int*)(ws + OFF_IDX) + row * K_;
#pragma unroll
    for (int j = 0; j < K_; ++j) { wp[j] = e[j] * sc; ip[j] = seli[base + j]; }
  }
}

// K5b: mixing commuted past t-contraction, n-minor layouts. grid(192,B) x 256
__global__ void k5b_mix(float* __restrict__ ws) {
  int c = blockIdx.x, b = blockIdx.y;
  const float* Xrow = ws + OFF_XPT + ((size_t)(b * 192 + c)) * NR;
  for (int it = 0; it < 4; ++it) {
    int n = it * 256 + threadIdx.x;
    if (n >= N_) break;
    const float* wp = ws + OFF_WGT + ((size_t)(b * N_ + n)) * K_;
    const int* ip = (const int*)(ws + OFF_IDX) + ((size_t)(b * N_ + n)) * K_;
    float acc = Xrow[n];
#pragma unroll
    for (int j = 0; j < K_; ++j) acc += wp[j] * Xrow[ip[j]];
    if (c < P_) ws[OFF_Y1T + ((size_t)(b * P_ + c)) * NR + n] = acc;
    else ws[OFF_ZST + ((size_t)(b * P_ + (c - P_))) * NR + n] = ws[OFF_DINV + n] * acc;
  }
}

// K6: CSR sparse A_hat @ Zs + final assembly, fully coalesced. grid(4,384) x 256
__global__ void k6_final(const float* __restrict__ A, const float* __restrict__ bhead,
                         const float* __restrict__ ggcn, const float* __restrict__ ws,
                         float* __restrict__ out) {
  int c = blockIdx.y;            // b*96+p
  int n = blockIdx.x * 256 + threadIdx.x;
  if (n >= N_) return;
  int p = c % P_;
  float gg = ggcn[0];
  const float* Zrow = ws + OFF_ZST + (size_t)c * NR;
  int cnt = ((const int*)(ws + OFF_CNT))[n];
  float S = 0.f;
  if (cnt >= 0) {
    const float* vv = ws + OFF_CSRV;
    const int* ii = (const int*)(ws + OFF_CSRI);
    for (int j = 0; j < cnt; ++j) S += vv[j * 864 + n] * Zrow[ii[j * 864 + n]];
  } else {
    const float* ar = A + (size_t)n * N_;
    for (int m = 0; m < N_; ++m) { float a = ar[m]; if (a != 0.f) S += a * Zrow[m]; }
  }
  float val = ws[OFF_Y1T + (size_t)c * NR + n]
            + gg * (ws[OFF_DINV + n] * S + ws[OFF_AROW + n] * ws[OFF_PA + p])
            + ws[OFF_PC + p] + bhead[p];
  out[(size_t)c * N_ + n] = val;
}

extern "C" void kernel_launch(void* const* d_in, const int* in_sizes, int n_in,
                              void* d_out, int out_size, void* d_ws, size_t ws_size,
                              hipStream_t stream) {
  const float* x     = (const float*)d_in[0];
  const float* We    = (const float*)d_in[1];
  const float* be    = (const float*)d_in[2];
  const float* W1    = (const float*)d_in[3];
  const float* W2    = (const float*)d_in[4];
  const float* gate  = (const float*)d_in[5];
  const float* A     = (const float*)d_in[6];
  const float* Wgcn  = (const float*)d_in[7];
  const float* ggcn  = (const float*)d_in[8];
  const float* Whead = (const float*)d_in[9];
  const float* bhead = (const float*)d_in[10];
  float* ws = (float*)d_ws;
  float* out = (float*)d_out;

  k0_scalars<<<1, 64, 0, stream>>>(We, be, W1, W2, gate, Wgcn, ws);
  k1b_dinv<<<N_, 64, 0, stream>>>(A, ws);
  k_csr<<<N_, 64, 0, stream>>>(A, ws);
  k4_proj<<<48, 192, 0, stream>>>(Whead, We, ws);
  k5_gemm<<<dim3(54, B_), 192, 0, stream>>>(x, ws);
  k2_topk<<<B_, 256, 0, stream>>>(ws);
  k5b_mix<<<dim3(192, B_), 256, 0, stream>>>(ws);
  k6_final<<<dim3(4, 384), 256, 0, stream>>>(A, bhead, ggcn, ws, out);
}

// Round 4
// 141.549 us; speedup vs baseline: 2.3048x; 1.1536x over previous
//
#include <hip/hip_runtime.h>
#include <math.h>

#define B_ 4
#define T_ 336
#define N_ 862
#define D_ 64
#define R_ 8
#define K_ 6
#define P_ 96
#define NR 896   // padded n-stride
#define CAP 32   // CSR cap per row
#define NB 864   // 864 = padded 862

// workspace float offsets
#define OFF_SCAL 0        // [0]=g,[1]=s11,[2]=s12,[3]=s21,[4]=s22
#define OFF_CB   16       // 64
#define OFF_WG1  80       // 64
#define OFF_WG2  144      // 64
#define OFF_PC   208      // 96
#define OFF_PA   304      // 96
#define OFF_XBAR 400      // 4*864 (t-sums, written whole by k5)
#define OFF_DINV 3856     // 864
#define OFF_WGT  4720     // 6*3456 (j-major: j*3456 + b*864 + n)
#define OFF_IDX  25456    // 6*3456 int
#define OFF_CNT  46192    // 864 int
#define OFF_CSRV 47056    // 32*864 (j-major)
#define OFF_CSRI 74704    // 32*864 int
#define OFF_P12  102352   // 336*192
#define OFF_XPT  166864   // 4*192*896 = 688128 (end 854992 floats)

// kB: per-row dinv + CSR compaction; block 0 additionally computes the
// gate/scalar precomputes and zeroes PC/PA. grid 862 x 64.
__global__ void kB_prep(const float* __restrict__ A, const float* __restrict__ We,
                        const float* __restrict__ be, const float* __restrict__ W1,
                        const float* __restrict__ W2, const float* __restrict__ gate,
                        const float* __restrict__ Wgcn, float* __restrict__ ws) {
  int n = blockIdx.x;
  int lane = threadIdx.x;
  const float* ap = A + (size_t)n * N_;
  float* vout = ws + OFF_CSRV;
  int* iout = (int*)(ws + OFF_CSRI);
  float s = 0.f;
  int total = 0;
  for (int base = 0; base < N_; base += 64) {
    int m = base + lane;
    float a = (m < N_) ? ap[m] : 0.f;
    s += a;
    bool nz = (a != 0.f);
    unsigned long long mask = __ballot(nz);
    int pos = __popcll(mask & ((1ull << lane) - 1ull));
    if (nz) {
      int slot = total + pos;
      if (slot < CAP) { vout[slot * NB + n] = a; iout[slot * NB + n] = m; }
    }
    total += __popcll(mask);
  }
  for (int off = 32; off; off >>= 1) s += __shfl_down(s, off);
  if (lane == 0) {
    ws[OFF_DINV + n] = (s > 0.f) ? (1.f / sqrtf(s)) : 0.f;
    ((int*)(ws + OFF_CNT))[n] = (total <= CAP) ? total : -1;
  }
  if (n == 0) {
    __shared__ float sc1[R_], sd1[R_], sc2[R_], sd2[R_];
    float g = 1.f / (1.f + expf(-gate[0]));
    if (lane < R_) {
      float a = 0.f, b = 0.f, c = 0.f, d = 0.f;
      for (int dd = 0; dd < D_; ++dd) {
        float w1 = W1[dd * R_ + lane], w2 = W2[dd * R_ + lane];
        a += We[dd] * w1; b += be[dd] * w1;
        c += We[dd] * w2; d += be[dd] * w2;
      }
      sc1[lane] = a; sd1[lane] = b; sc2[lane] = c; sd2[lane] = d;
    }
    __syncthreads();
    if (lane == 0) {
      float s11 = 0.f, s12 = 0.f, s21 = 0.f, s22 = 0.f;
      for (int r = 0; r < R_; ++r) {
        s11 += sc1[r] * sc2[r];
        s12 += sc1[r] * sd2[r];
        s21 += sd1[r] * sc2[r];
        s22 += sd1[r] * sd2[r];
      }
      ws[0] = g; ws[1] = s11; ws[2] = s12; ws[3] = s21; ws[4] = s22;
    }
    ws[OFF_CB + lane] = (1.f + g) * be[lane];
    float wg1 = 0.f, wg2 = 0.f;
    for (int dd = 0; dd < D_; ++dd) {
      float w = Wgcn[dd * D_ + lane];
      wg1 += We[dd] * w;
      wg2 += (1.f + g) * be[dd] * w;
    }
    ws[OFF_WG1 + lane] = wg1;
    ws[OFF_WG2 + lane] = wg2;
    ws[OFF_PC + lane] = 0.f;
    ws[OFF_PC + 64 + lane] = 0.f;
    ws[OFF_PC + 128 + lane] = 0.f;
  }
}

// K4: P12[t][c]; atomic Pc/Pa. grid 336 x 192 (1 t per block).
__global__ void k4_proj(const float* __restrict__ Whead, const float* __restrict__ We,
                        float* __restrict__ ws) {
  int t = blockIdx.x;
  int c = threadIdx.x;
  int p = c % P_;
  int sel = c / P_;
  const float* cA = sel ? (ws + OFF_WG1) : We;
  const float* cB = sel ? (ws + OFF_WG2) : (ws + OFF_CB);
  const float* wrow = Whead + (size_t)t * D_ * P_ + p;
  float a = 0.f, bacc = 0.f;
#pragma unroll 8
  for (int e = 0; e < D_; ++e) {
    float w = wrow[(size_t)e * P_];
    a += cA[e] * w;
    bacc += cB[e] * w;
  }
  ws[OFF_P12 + t * 192 + c] = a;
  atomicAdd(&ws[OFF_PC + c], bacc);
}

// K5: XpT[(b*192+c)*NR + n] = sum_t x[b,t,n] * P12[t,c]; also xbar t-sums.
// grid(54,B) x 192. Block tile 16n x 192c, BK=48. Thread: 4c x 4n.
__global__ __launch_bounds__(192) void k5_gemm(const float* __restrict__ x,
                                               float* __restrict__ ws) {
  __shared__ float xs[48 * 16];
  __shared__ float ps[48 * 192];
  int b = blockIdx.y;
  int n0 = blockIdx.x * 16;
  int tid = threadIdx.x;
  int cq = tid % 48, nq = tid / 48;   // nq in [0,4)
  int c0 = cq * 4;
  const float* P = ws + OFF_P12;
  float acc[4][4];
#pragma unroll
  for (int i = 0; i < 4; ++i)
#pragma unroll
    for (int j = 0; j < 4; ++j) acc[i][j] = 0.f;
  float colsum = 0.f;
  int xrow = tid >> 2, xcol4 = tid & 3;
  for (int kc = 0; kc < 7; ++kc) {
    int t0 = kc * 48;
    {
      const float* xr = x + (size_t)(b * T_ + t0 + xrow) * N_;
      if (n0 + 15 < N_) {
        *(float4*)(xs + xrow * 16 + xcol4 * 4) = *(const float4*)(xr + n0 + xcol4 * 4);
      } else {
        float* dst = xs + xrow * 16 + xcol4 * 4;
#pragma unroll
        for (int q = 0; q < 4; ++q) {
          int nn = n0 + xcol4 * 4 + q; if (nn > N_ - 1) nn = N_ - 1;
          dst[q] = xr[nn];
        }
      }
    }
#pragma unroll
    for (int sIdx = 0; sIdx < 12; ++sIdx) {
      int i4 = tid + sIdx * 192;
      int row = i4 / 48, col4 = i4 % 48;
      *(float4*)(ps + row * 192 + col4 * 4) =
          *(const float4*)(P + (size_t)(t0 + row) * 192 + col4 * 4);
    }
    __syncthreads();
    if (tid < 16) {
#pragma unroll 8
      for (int kk = 0; kk < 48; ++kk) colsum += xs[kk * 16 + tid];
    }
#pragma unroll 4
    for (int kk = 0; kk < 48; ++kk) {
      float4 xv = *(const float4*)(xs + kk * 16 + nq * 4);
      float4 pv = *(const float4*)(ps + kk * 192 + c0);
      acc[0][0] = fmaf(pv.x, xv.x, acc[0][0]); acc[0][1] = fmaf(pv.x, xv.y, acc[0][1]);
      acc[0][2] = fmaf(pv.x, xv.z, acc[0][2]); acc[0][3] = fmaf(pv.x, xv.w, acc[0][3]);
      acc[1][0] = fmaf(pv.y, xv.x, acc[1][0]); acc[1][1] = fmaf(pv.y, xv.y, acc[1][1]);
      acc[1][2] = fmaf(pv.y, xv.z, acc[1][2]); acc[1][3] = fmaf(pv.y, xv.w, acc[1][3]);
      acc[2][0] = fmaf(pv.z, xv.x, acc[2][0]); acc[2][1] = fmaf(pv.z, xv.y, acc[2][1]);
      acc[2][2] = fmaf(pv.z, xv.z, acc[2][2]); acc[2][3] = fmaf(pv.z, xv.w, acc[2][3]);
      acc[3][0] = fmaf(pv.w, xv.x, acc[3][0]); acc[3][1] = fmaf(pv.w, xv.y, acc[3][1]);
      acc[3][2] = fmaf(pv.w, xv.z, acc[3][2]); acc[3][3] = fmaf(pv.w, xv.w, acc[3][3]);
    }
    __syncthreads();
  }
#pragma unroll
  for (int cc = 0; cc < 4; ++cc) {
    float4 v;
    v.x = acc[cc][0]; v.y = acc[cc][1]; v.z = acc[cc][2]; v.w = acc[cc][3];
    *(float4*)(ws + OFF_XPT + ((size_t)(b * 192 + c0 + cc)) * NR + n0 + nq * 4) = v;
  }
  if (tid < 16 && n0 + tid < N_) ws[OFF_XBAR + b * NB + n0 + tid] = colsum;
}

// K2: per-batch top-6 / bottom-6 of xbar (concurrent dual extraction),
// then per-n softmax weights. grid B x 256.
__global__ void k2_topk(float* __restrict__ ws) {
  __shared__ float sx[NB];
  __shared__ float wkmax[NB], wkmin[NB];
  __shared__ float wbest[4];
  __shared__ int wbi[4];
  __shared__ float selv[12];
  __shared__ int seli[12];
  int b = blockIdx.x;
  int tid = threadIdx.x;
  const float invT = 1.f / (float)T_;
  for (int i = tid; i < NB; i += 256) {
    float v = (i < N_) ? ws[OFF_XBAR + b * NB + i] * invT : 0.f;
    sx[i] = v;
    wkmax[i] = (i < N_) ? v : -3.4e38f;
    wkmin[i] = (i < N_) ? v : 3.4e38f;
  }
  __syncthreads();
  int side = tid >> 7;           // 0: max (threads 0-127), 1: min (128-255)
  int stid = tid & 127;
  int lane = tid & 63, wvid = tid >> 6;  // waves 0,1 -> max; 2,3 -> min
  for (int r = 0; r < K_; ++r) {
    float bv = side ? 3.4e38f : -3.4e38f;
    int bi = 0;
    const float* wk = side ? wkmin : wkmax;
    for (int i = stid; i < N_; i += 128) {
      float v = wk[i];
      bool better = side ? (v < bv) : (v > bv);
      if (better) { bv = v; bi = i; }
    }
    for (int off = 32; off; off >>= 1) {
      float ov = __shfl_down(bv, off);
      int oi = __shfl_down(bi, off);
      bool better = side ? (ov < bv) : (ov > bv);
      if (better) { bv = ov; bi = oi; }
    }
    if (lane == 0) { wbest[wvid] = bv; wbi[wvid] = bi; }
    __syncthreads();
    if (tid == 0) {
      float mv = wbest[0]; int mi = wbi[0];
      if (wbest[1] > mv) { mv = wbest[1]; mi = wbi[1]; }
      selv[r] = mv; seli[r] = mi;
      wkmax[mi] = -3.4e38f;
    }
    if (tid == 128) {
      float mv = wbest[2]; int mi = wbi[2];
      if (wbest[3] < mv) { mv = wbest[3]; mi = wbi[3]; }
      selv[6 + r] = mv; seli[6 + r] = mi;
      wkmin[mi] = 3.4e38f;
    }
    __syncthreads();
  }
  float s11 = ws[1], s12 = ws[2], s21 = ws[3], s22 = ws[4], g = ws[0];
  const float rsq = 0.3535533906f;
  for (int n = tid; n < N_; n += 256) {
    float xn = sx[n];
    float alpha = (xn * s11 + s21) * rsq;
    float beta  = (xn * s12 + s22) * rsq;
    int base = (alpha >= 0.f) ? 0 : 6;
    float l[K_]; float mx = -3.4e38f;
#pragma unroll
    for (int j = 0; j < K_; ++j) { l[j] = alpha * selv[base + j] + beta; mx = fmaxf(mx, l[j]); }
    float e[K_]; float ss = 0.f;
#pragma unroll
    for (int j = 0; j < K_; ++j) { e[j] = expf(l[j] - mx); ss += e[j]; }
    float sc = g / ss;
#pragma unroll
    for (int j = 0; j < K_; ++j) {
      ws[OFF_WGT + j * (4 * NB) + b * NB + n] = e[j] * sc;
      ((int*)(ws + OFF_IDX))[j * (4 * NB) + b * NB + n] = seli[base + j];
    }
  }
}

// K6: everything fused — mix1, on-the-fly Zs (mix2 + PA), CSR A_hat gather,
// final assembly. grid(4,384) x 256. blockIdx.y = c = b*96+p.
__global__ void k6_final(const float* __restrict__ A, const float* __restrict__ bhead,
                         const float* __restrict__ ggcn, const float* __restrict__ ws,
                         float* __restrict__ out) {
  int c = blockIdx.y;
  int n = blockIdx.x * 256 + threadIdx.x;
  if (n >= N_) return;
  int b = c / P_, p = c % P_;
  const float* Xp1 = ws + OFF_XPT + ((size_t)(b * 192 + p)) * NR;
  const float* Xp2 = ws + OFF_XPT + ((size_t)(b * 192 + P_ + p)) * NR;
  const float* WGTb = ws + OFF_WGT + b * NB;
  const int* IDXb = (const int*)(ws + OFF_IDX) + b * NB;
  float gg = ggcn[0];
  float PAp = ws[OFF_PA + p];
  // mix1 at n
  float acc1 = Xp1[n];
#pragma unroll
  for (int j = 0; j < K_; ++j)
    acc1 += WGTb[j * (4 * NB) + n] * Xp1[IDXb[j * (4 * NB) + n]];
  // S_full = sum_m A[n,m] * dinv[m] * (mix2(m) + PA[p])
  int cnt = ((const int*)(ws + OFF_CNT))[n];
  float S = 0.f;
  if (cnt >= 0) {
    const float* vv = ws + OFF_CSRV;
    const int* ii = (const int*)(ws + OFF_CSRI);
    for (int jj = 0; jj < cnt; ++jj) {
      float a = vv[jj * NB + n];
      int m = ii[jj * NB + n];
      float mix2 = Xp2[m];
#pragma unroll
      for (int j = 0; j < K_; ++j)
        mix2 += WGTb[j * (4 * NB) + m] * Xp2[IDXb[j * (4 * NB) + m]];
      S += a * ws[OFF_DINV + m] * (mix2 + PAp);
    }
  } else {
    const float* ar = A + (size_t)n * N_;
    for (int m = 0; m < N_; ++m) {
      float a = ar[m];
      if (a != 0.f) {
        float mix2 = Xp2[m];
#pragma unroll
        for (int j = 0; j < K_; ++j)
          mix2 += WGTb[j * (4 * NB) + m] * Xp2[IDXb[j * (4 * NB) + m]];
        S += a * ws[OFF_DINV + m] * (mix2 + PAp);
      }
    }
  }
  out[(size_t)c * N_ + n] = acc1 + gg * ws[OFF_DINV + n] * S
                          + ws[OFF_PC + p] + bhead[p];
}

extern "C" void kernel_launch(void* const* d_in, const int* in_sizes, int n_in,
                              void* d_out, int out_size, void* d_ws, size_t ws_size,
                              hipStream_t stream) {
  const float* x     = (const float*)d_in[0];
  const float* We    = (const float*)d_in[1];
  const float* be    = (const float*)d_in[2];
  const float* W1    = (const float*)d_in[3];
  const float* W2    = (const float*)d_in[4];
  const float* gate  = (const float*)d_in[5];
  const float* A     = (const float*)d_in[6];
  const float* Wgcn  = (const float*)d_in[7];
  const float* ggcn  = (const float*)d_in[8];
  const float* Whead = (const float*)d_in[9];
  const float* bhead = (const float*)d_in[10];
  float* ws = (float*)d_ws;
  float* out = (float*)d_out;

  kB_prep<<<N_, 64, 0, stream>>>(A, We, be, W1, W2, gate, Wgcn, ws);
  k4_proj<<<T_, 192, 0, stream>>>(Whead, We, ws);
  k5_gemm<<<dim3(54, B_), 192, 0, stream>>>(x, ws);
  k2_topk<<<B_, 256, 0, stream>>>(ws);
  k6_final<<<dim3(4, 384), 256, 0, stream>>>(A, bhead, ggcn, ws, out);
}

// Round 5
// 135.343 us; speedup vs baseline: 2.4105x; 1.0459x over previous
//
#include <hip/hip_runtime.h>
#include <math.h>

#define B_ 4
#define T_ 336
#define N_ 862
#define D_ 64
#define R_ 8
#define K_ 6
#define P_ 96
#define NR 896   // padded n-stride
#define CAP 32   // CSR cap per row
#define NB 864   // padded 862

// workspace float offsets
#define OFF_PC   0        // 192: PC (96) then PA (96)
#define OFF_XBAR 192      // 4*864 raw t-sums
#define OFF_DINV 3648     // 864
#define OFF_WGT  4512     // 6*3456 (j-major: j*3456 + b*864 + n)
#define OFF_IDX  25248    // 6*3456 int
#define OFF_CNT  45984    // 864 int
#define OFF_CSRV 46848    // 32*864 (j-major)
#define OFF_CSRI 74496    // 32*864 int
#define OFF_P12  102144   // 336*192
#define OFF_PCP  166656   // 336*192 per-t partials of PC/PA
#define OFF_XPT  231168   // 4*192*896 = 688128 (end 919296 floats)

// ---------------- Phase A: Whead projections (336 blocks) + xbar (56 blocks).
// grid 392 x 192.
__global__ __launch_bounds__(192) void kA_prep(const float* __restrict__ x,
                                               const float* __restrict__ Whead,
                                               const float* __restrict__ We,
                                               const float* __restrict__ be,
                                               const float* __restrict__ gate,
                                               const float* __restrict__ Wgcn,
                                               float* __restrict__ ws) {
  int id = blockIdx.x;
  int tid = threadIdx.x;
  if (id < 336) {
    // ---- projection for t = id: P12[t][c], PCP[t][c]
    __shared__ float sW1[64], sW2[64], sCB[64], sWe[64];
    int t = id;
    float g = 1.f / (1.f + expf(-gate[0]));
    if (tid < 64) {
      float a = 0.f;
#pragma unroll 8
      for (int dd = 0; dd < D_; ++dd) a += We[dd] * Wgcn[dd * D_ + tid];
      sW1[tid] = a;
    } else if (tid < 128) {
      int e = tid - 64;
      float a = 0.f;
#pragma unroll 8
      for (int dd = 0; dd < D_; ++dd) a += be[dd] * Wgcn[dd * D_ + e];
      sW2[e] = (1.f + g) * a;
    } else {
      int e = tid - 128;
      sCB[e] = (1.f + g) * be[e];
      sWe[e] = We[e];
    }
    __syncthreads();
    int c = tid, p = c % P_, sel = c / P_;
    const float* cA = sel ? sW1 : sWe;
    const float* cB = sel ? sW2 : sCB;
    const float* wrow = Whead + (size_t)t * D_ * P_ + p;
    float a = 0.f, bacc = 0.f;
#pragma unroll 8
    for (int e = 0; e < D_; ++e) {
      float w = wrow[(size_t)e * P_];
      a = fmaf(cA[e], w, a);
      bacc = fmaf(cB[e], w, bacc);
    }
    ws[OFF_P12 + t * 192 + c] = a;
    ws[OFF_PCP + t * 192 + c] = bacc;
  } else {
    // ---- xbar t-sums: block owns (b, 64-n chunk)
    __shared__ float part[192];
    int iq = id - 336;
    int b = iq / 14, ch = iq % 14;
    int lane = tid & 63, tg = tid >> 6;
    int n = ch * 64 + lane;
    float s = 0.f;
    if (n < N_) {
      const float* xp = x + (size_t)(b * T_) * N_ + n;
      for (int t = tg; t < T_; t += 3) s += xp[(size_t)t * N_];
    }
    part[tid] = s;
    __syncthreads();
    if (tg == 0 && n < N_)
      ws[OFF_XBAR + b * NB + n] = part[lane] + part[64 + lane] + part[128 + lane];
  }
}

// ---------------- Phase B: GEMM (216) + topk (4) + CSR (288) + PC/PA reduce (1).
// grid 509 x 192.
__global__ __launch_bounds__(192) void kM_mid(const float* __restrict__ x,
                                              const float* __restrict__ A,
                                              const float* __restrict__ W1,
                                              const float* __restrict__ W2,
                                              const float* __restrict__ We,
                                              const float* __restrict__ be,
                                              const float* __restrict__ gate,
                                              float* __restrict__ ws) {
  __shared__ float smem[9984];
  int id = blockIdx.x;
  int tid = threadIdx.x;
  if (id < 216) {
    // ---- GEMM: XpT[(b*192+c)*NR + n] = sum_t x[b,t,n] * P12[t,c]
    float* xs = smem;          // 48*16
    float* ps = smem + 768;    // 48*192
    int b = id / 54;
    int n0 = (id % 54) * 16;
    int cq = tid % 48, nq = tid / 48;
    int c0 = cq * 4;
    const float* P = ws + OFF_P12;
    float acc[4][4];
#pragma unroll
    for (int i = 0; i < 4; ++i)
#pragma unroll
      for (int j = 0; j < 4; ++j) acc[i][j] = 0.f;
    int xrow = tid >> 2, xcol4 = tid & 3;
    for (int kc = 0; kc < 7; ++kc) {
      int t0 = kc * 48;
      {
        const float* xr = x + (size_t)(b * T_ + t0 + xrow) * N_;
        if (n0 + 15 < N_) {
          *(float4*)(xs + xrow * 16 + xcol4 * 4) = *(const float4*)(xr + n0 + xcol4 * 4);
        } else {
          float* dst = xs + xrow * 16 + xcol4 * 4;
#pragma unroll
          for (int q = 0; q < 4; ++q) {
            int nn = n0 + xcol4 * 4 + q; if (nn > N_ - 1) nn = N_ - 1;
            dst[q] = xr[nn];
          }
        }
      }
#pragma unroll
      for (int sIdx = 0; sIdx < 12; ++sIdx) {
        int i4 = tid + sIdx * 192;
        int row = i4 / 48, col4 = i4 % 48;
        *(float4*)(ps + row * 192 + col4 * 4) =
            *(const float4*)(P + (size_t)(t0 + row) * 192 + col4 * 4);
      }
      __syncthreads();
#pragma unroll 4
      for (int kk = 0; kk < 48; ++kk) {
        float4 xv = *(const float4*)(xs + kk * 16 + nq * 4);
        float4 pv = *(const float4*)(ps + kk * 192 + c0);
        acc[0][0] = fmaf(pv.x, xv.x, acc[0][0]); acc[0][1] = fmaf(pv.x, xv.y, acc[0][1]);
        acc[0][2] = fmaf(pv.x, xv.z, acc[0][2]); acc[0][3] = fmaf(pv.x, xv.w, acc[0][3]);
        acc[1][0] = fmaf(pv.y, xv.x, acc[1][0]); acc[1][1] = fmaf(pv.y, xv.y, acc[1][1]);
        acc[1][2] = fmaf(pv.y, xv.z, acc[1][2]); acc[1][3] = fmaf(pv.y, xv.w, acc[1][3]);
        acc[2][0] = fmaf(pv.z, xv.x, acc[2][0]); acc[2][1] = fmaf(pv.z, xv.y, acc[2][1]);
        acc[2][2] = fmaf(pv.z, xv.z, acc[2][2]); acc[2][3] = fmaf(pv.z, xv.w, acc[2][3]);
        acc[3][0] = fmaf(pv.w, xv.x, acc[3][0]); acc[3][1] = fmaf(pv.w, xv.y, acc[3][1]);
        acc[3][2] = fmaf(pv.w, xv.z, acc[3][2]); acc[3][3] = fmaf(pv.w, xv.w, acc[3][3]);
      }
      __syncthreads();
    }
#pragma unroll
    for (int cc = 0; cc < 4; ++cc) {
      float4 v;
      v.x = acc[cc][0]; v.y = acc[cc][1]; v.z = acc[cc][2]; v.w = acc[cc][3];
      *(float4*)(ws + OFF_XPT + ((size_t)(b * 192 + c0 + cc)) * NR + n0 + nq * 4) = v;
    }
  } else if (id < 220) {
    // ---- top-6 / bottom-6 of xbar for batch b, then softmax weights
    __shared__ float s_sc[4][R_];
    __shared__ float s_scal[5];
    __shared__ float selv[12];
    __shared__ int seli[12];
    float* sx = smem;            // 864
    float* wkmax = smem + 864;   // 864
    float* wkmin = smem + 1728;  // 864
    int b = id - 216;
    // scalars: s11,s12,s21,s22 + g
    if (tid < 16) {
      int r = tid & 7, which = tid >> 3;
      const float* W = which ? W2 : W1;
      float a = 0.f, bb = 0.f;
      for (int dd = 0; dd < D_; ++dd) {
        float w = W[dd * R_ + r];
        a += We[dd] * w; bb += be[dd] * w;
      }
      s_sc[which * 2][r] = a; s_sc[which * 2 + 1][r] = bb;
    }
    const float invT = 1.f / (float)T_;
    for (int i = tid; i < NB; i += 192) {
      float v = (i < N_) ? ws[OFF_XBAR + b * NB + i] * invT : 0.f;
      sx[i] = v;
      wkmax[i] = (i < N_) ? v : -3.4e38f;
      wkmin[i] = (i < N_) ? v : 3.4e38f;
    }
    __syncthreads();
    if (tid == 0) {
      float s11 = 0.f, s12 = 0.f, s21 = 0.f, s22 = 0.f;
      for (int r = 0; r < R_; ++r) {
        s11 += s_sc[0][r] * s_sc[2][r];
        s12 += s_sc[0][r] * s_sc[3][r];
        s21 += s_sc[1][r] * s_sc[2][r];
        s22 += s_sc[1][r] * s_sc[3][r];
      }
      s_scal[0] = s11; s_scal[1] = s12; s_scal[2] = s21; s_scal[3] = s22;
      s_scal[4] = 1.f / (1.f + expf(-gate[0]));
    }
    // wave0: 6 max rounds; wave1: 6 min rounds (wave-synchronous LDS)
    if (tid < 64) {
      int lane = tid;
      for (int r = 0; r < K_; ++r) {
        float bv = -3.4e38f; int bi = 0;
        for (int i = lane; i < N_; i += 64) {
          float v = wkmax[i];
          if (v > bv) { bv = v; bi = i; }
        }
        for (int off = 32; off; off >>= 1) {
          float ov = __shfl_down(bv, off);
          int oi = __shfl_down(bi, off);
          if (ov > bv) { bv = ov; bi = oi; }
        }
        bv = __shfl(bv, 0); bi = __shfl(bi, 0);
        if (lane == 0) { selv[r] = bv; seli[r] = bi; wkmax[bi] = -3.4e38f; }
      }
    } else if (tid < 128) {
      int lane = tid - 64;
      for (int r = 0; r < K_; ++r) {
        float bv = 3.4e38f; int bi = 0;
        for (int i = lane; i < N_; i += 64) {
          float v = wkmin[i];
          if (v < bv) { bv = v; bi = i; }
        }
        for (int off = 32; off; off >>= 1) {
          float ov = __shfl_down(bv, off);
          int oi = __shfl_down(bi, off);
          if (ov < bv) { bv = ov; bi = oi; }
        }
        bv = __shfl(bv, 0); bi = __shfl(bi, 0);
        if (lane == 0) { selv[6 + r] = bv; seli[6 + r] = bi; wkmin[bi] = 3.4e38f; }
      }
    }
    __syncthreads();
    float s11 = s_scal[0], s12 = s_scal[1], s21 = s_scal[2], s22 = s_scal[3];
    float g = s_scal[4];
    const float rsq = 0.3535533906f;
    for (int n = tid; n < N_; n += 192) {
      float xn = sx[n];
      float alpha = (xn * s11 + s21) * rsq;
      float beta  = (xn * s12 + s22) * rsq;
      int base = (alpha >= 0.f) ? 0 : 6;
      float l[K_]; float mx = -3.4e38f;
#pragma unroll
      for (int j = 0; j < K_; ++j) { l[j] = alpha * selv[base + j] + beta; mx = fmaxf(mx, l[j]); }
      float e[K_]; float ss = 0.f;
#pragma unroll
      for (int j = 0; j < K_; ++j) { e[j] = expf(l[j] - mx); ss += e[j]; }
      float sc = g / ss;
#pragma unroll
      for (int j = 0; j < K_; ++j) {
        ws[OFF_WGT + j * (4 * NB) + b * NB + n] = e[j] * sc;
        ((int*)(ws + OFF_IDX))[j * (4 * NB) + b * NB + n] = seli[base + j];
      }
    }
  } else if (id < 508) {
    // ---- CSR + dinv: 3 rows per block, one per wave
    int lane = tid & 63, wv = tid >> 6;
    int n = (id - 220) * 3 + wv;
    if (n >= N_) return;
    const float* ap = A + (size_t)n * N_;
    float* vout = ws + OFF_CSRV;
    int* iout = (int*)(ws + OFF_CSRI);
    float s = 0.f;
    int total = 0;
    for (int base = 0; base < N_; base += 64) {
      int m = base + lane;
      float a = (m < N_) ? ap[m] : 0.f;
      s += a;
      bool nz = (a != 0.f);
      unsigned long long mask = __ballot(nz);
      int pos = __popcll(mask & ((1ull << lane) - 1ull));
      if (nz) {
        int slot = total + pos;
        if (slot < CAP) { vout[slot * NB + n] = a; iout[slot * NB + n] = m; }
      }
      total += __popcll(mask);
    }
    for (int off = 32; off; off >>= 1) s += __shfl_down(s, off);
    if (lane == 0) {
      ws[OFF_DINV + n] = (s > 0.f) ? (1.f / sqrtf(s)) : 0.f;
      ((int*)(ws + OFF_CNT))[n] = (total <= CAP) ? total : -1;
    }
  } else {
    // ---- PC/PA column reduce over t
    int c = tid;
    float s = 0.f;
    for (int t = 0; t < T_; ++t) s += ws[OFF_PCP + t * 192 + c];
    ws[OFF_PC + c] = s;
  }
}

// ---------------- Phase C: fused mix1 + on-the-fly GCN + assembly.
// grid(4,384) x 256. blockIdx.y = c = b*96+p.
__global__ void kF_final(const float* __restrict__ A, const float* __restrict__ bhead,
                         const float* __restrict__ ggcn, const float* __restrict__ ws,
                         float* __restrict__ out) {
  int c = blockIdx.y;
  int n = blockIdx.x * 256 + threadIdx.x;
  if (n >= N_) return;
  int b = c / P_, p = c % P_;
  const float* Xp1 = ws + OFF_XPT + ((size_t)(b * 192 + p)) * NR;
  const float* Xp2 = ws + OFF_XPT + ((size_t)(b * 192 + P_ + p)) * NR;
  const float* WGTb = ws + OFF_WGT + b * NB;
  const int* IDXb = (const int*)(ws + OFF_IDX) + b * NB;
  float gg = ggcn[0];
  float PAp = ws[OFF_PC + 96 + p];
  float acc1 = Xp1[n];
#pragma unroll
  for (int j = 0; j < K_; ++j)
    acc1 += WGTb[j * (4 * NB) + n] * Xp1[IDXb[j * (4 * NB) + n]];
  int cnt = ((const int*)(ws + OFF_CNT))[n];
  float S = 0.f;
  if (cnt >= 0) {
    const float* vv = ws + OFF_CSRV;
    const int* ii = (const int*)(ws + OFF_CSRI);
    for (int jj = 0; jj < cnt; ++jj) {
      float a = vv[jj * NB + n];
      int m = ii[jj * NB + n];
      float mix2 = Xp2[m];
#pragma unroll
      for (int j = 0; j < K_; ++j)
        mix2 += WGTb[j * (4 * NB) + m] * Xp2[IDXb[j * (4 * NB) + m]];
      S += a * ws[OFF_DINV + m] * (mix2 + PAp);
    }
  } else {
    const float* ar = A + (size_t)n * N_;
    for (int m = 0; m < N_; ++m) {
      float a = ar[m];
      if (a != 0.f) {
        float mix2 = Xp2[m];
#pragma unroll
        for (int j = 0; j < K_; ++j)
          mix2 += WGTb[j * (4 * NB) + m] * Xp2[IDXb[j * (4 * NB) + m]];
        S += a * ws[OFF_DINV + m] * (mix2 + PAp);
      }
    }
  }
  out[(size_t)c * N_ + n] = acc1 + gg * ws[OFF_DINV + n] * S
                          + ws[OFF_PC + p] + bhead[p];
}

extern "C" void kernel_launch(void* const* d_in, const int* in_sizes, int n_in,
                              void* d_out, int out_size, void* d_ws, size_t ws_size,
                              hipStream_t stream) {
  const float* x     = (const float*)d_in[0];
  const float* We    = (const float*)d_in[1];
  const float* be    = (const float*)d_in[2];
  const float* W1    = (const float*)d_in[3];
  const float* W2    = (const float*)d_in[4];
  const float* gate  = (const float*)d_in[5];
  const float* A     = (const float*)d_in[6];
  const float* Wgcn  = (const float*)d_in[7];
  const float* ggcn  = (const float*)d_in[8];
  const float* Whead = (const float*)d_in[9];
  const float* bhead = (const float*)d_in[10];
  float* ws = (float*)d_ws;
  float* out = (float*)d_out;

  kA_prep<<<392, 192, 0, stream>>>(x, Whead, We, be, gate, Wgcn, ws);
  kM_mid<<<509, 192, 0, stream>>>(x, A, W1, W2, We, be, gate, ws);
  kF_final<<<dim3(4, 384), 256, 0, stream>>>(A, bhead, ggcn, ws, out);
}

// Round 6
// 113.091 us; speedup vs baseline: 2.8848x; 1.1968x over previous
//
#include <hip/hip_runtime.h>
#include <math.h>

#define B_ 4
#define T_ 336
#define N_ 862
#define D_ 64
#define R_ 8
#define K_ 6
#define P_ 96
#define NR 896   // padded n-stride
#define CAP 32   // CSR cap per row
#define NB 864   // padded 862

// workspace float offsets
#define OFF_PCQ  0        // 4*192 partial PC/PA
#define OFF_XBP  768      // 4*6*864 xbar t-partials
#define OFF_DINV 21504    // 864
#define OFF_WGT  22368    // 6*3456 (j-major: j*3456 + b*864 + n)
#define OFF_IDX  43104    // 6*3456 int
#define OFF_CNT  63840    // 864 int
#define OFF_CSRV 64704    // 32*864 (j-major)
#define OFF_CSRI 92352    // 32*864 int
#define OFF_P12  120000   // 336*192
#define OFF_PCP  184512   // 336*192 per-t partials of PC/PA
#define OFF_XPT  249024   // 4*192*896 = 688128 (end 937152 floats)

// ---------------- Phase A: proj (336) + xbar partials (336) + CSR/dinv (288).
// grid 960 x 192.
__global__ __launch_bounds__(192) void kA_prep(const float* __restrict__ x,
                                               const float* __restrict__ Whead,
                                               const float* __restrict__ A,
                                               const float* __restrict__ We,
                                               const float* __restrict__ be,
                                               const float* __restrict__ gate,
                                               const float* __restrict__ Wgcn,
                                               float* __restrict__ ws) {
  int id = blockIdx.x;
  int tid = threadIdx.x;
  if (id < 336) {
    // ---- projection for t = id: P12[t][c], PCP[t][c]
    __shared__ float sW1[64], sW2[64], sCB[64], sWe[64];
    int t = id;
    float g = 1.f / (1.f + expf(-gate[0]));
    if (tid < 64) {
      float a = 0.f;
#pragma unroll
      for (int dd = 0; dd < D_; ++dd) a += We[dd] * Wgcn[dd * D_ + tid];
      sW1[tid] = a;
    } else if (tid < 128) {
      int e = tid - 64;
      float a = 0.f;
#pragma unroll
      for (int dd = 0; dd < D_; ++dd) a += be[dd] * Wgcn[dd * D_ + e];
      sW2[e] = (1.f + g) * a;
    } else {
      int e = tid - 128;
      sCB[e] = (1.f + g) * be[e];
      sWe[e] = We[e];
    }
    __syncthreads();
    int c = tid, p = c % P_, sel = c / P_;
    const float* cA = sel ? sW1 : sWe;
    const float* cB = sel ? sW2 : sCB;
    const float* wrow = Whead + (size_t)t * D_ * P_ + p;
    float a = 0.f, bacc = 0.f;
#pragma unroll
    for (int e = 0; e < D_; ++e) {
      float w = wrow[(size_t)e * P_];
      a = fmaf(cA[e], w, a);
      bacc = fmaf(cB[e], w, bacc);
    }
    ws[OFF_P12 + t * 192 + c] = a;
    ws[OFF_PCP + t * 192 + c] = bacc;
  } else if (id < 672) {
    // ---- xbar t-partials: block = (b, 64-n chunk, t-group of 56)
    __shared__ float part[192];
    int iq = id - 336;
    int b = iq / 84, rem = iq % 84;
    int ch = rem / 6, tg = rem % 6;
    int lane = tid & 63, tsub = tid >> 6;
    int n = ch * 64 + lane;
    float s = 0.f;
    if (n < N_) {
      const float* xp = x + (size_t)(b * T_) * N_ + n;
      int tend = tg * 56 + 56;
#pragma unroll 4
      for (int t = tg * 56 + tsub; t < tend; t += 3) s += xp[(size_t)t * N_];
    }
    part[tid] = s;
    __syncthreads();
    if (tsub == 0 && n < N_)
      ws[OFF_XBP + (size_t)(b * 6 + tg) * NB + n] =
          part[lane] + part[64 + lane] + part[128 + lane];
  } else {
    // ---- CSR + dinv: 3 rows per block, one per wave
    int lane = tid & 63, wv = tid >> 6;
    int n = (id - 672) * 3 + wv;
    if (n >= N_) return;
    const float* ap = A + (size_t)n * N_;
    float* vout = ws + OFF_CSRV;
    int* iout = (int*)(ws + OFF_CSRI);
    float s = 0.f;
    int total = 0;
    for (int base = 0; base < N_; base += 64) {
      int m = base + lane;
      float a = (m < N_) ? ap[m] : 0.f;
      s += a;
      bool nz = (a != 0.f);
      unsigned long long mask = __ballot(nz);
      int pos = __popcll(mask & ((1ull << lane) - 1ull));
      if (nz) {
        int slot = total + pos;
        if (slot < CAP) { vout[slot * NB + n] = a; iout[slot * NB + n] = m; }
      }
      total += __popcll(mask);
    }
    for (int off = 32; off; off >>= 1) s += __shfl_down(s, off);
    if (lane == 0) {
      ws[OFF_DINV + n] = (s > 0.f) ? (1.f / sqrtf(s)) : 0.f;
      ((int*)(ws + OFF_CNT))[n] = (total <= CAP) ? total : -1;
    }
  }
}

// ---------------- Phase B: GEMM (216) + topk (4) + PC/PA partials (4).
// grid 224 x 192.
__global__ __launch_bounds__(192) void kM_mid(const float* __restrict__ x,
                                              const float* __restrict__ W1,
                                              const float* __restrict__ W2,
                                              const float* __restrict__ We,
                                              const float* __restrict__ be,
                                              const float* __restrict__ gate,
                                              float* __restrict__ ws) {
  __shared__ float smem[9984];
  int id = blockIdx.x;
  int tid = threadIdx.x;
  if (id < 216) {
    // ---- GEMM: XpT[(b*192+c)*NR + n] = sum_t x[b,t,n] * P12[t,c]
    float* xs = smem;          // 48*16
    float* ps = smem + 768;    // 48*192
    int b = id / 54;
    int n0 = (id % 54) * 16;
    int cq = tid % 48, nq = tid / 48;
    int c0 = cq * 4;
    const float* P = ws + OFF_P12;
    float acc[4][4];
#pragma unroll
    for (int i = 0; i < 4; ++i)
#pragma unroll
      for (int j = 0; j < 4; ++j) acc[i][j] = 0.f;
    int xrow = tid >> 2, xcol4 = tid & 3;
    for (int kc = 0; kc < 7; ++kc) {
      int t0 = kc * 48;
      {
        const float* xr = x + (size_t)(b * T_ + t0 + xrow) * N_;
        if (n0 + 15 < N_) {
          *(float4*)(xs + xrow * 16 + xcol4 * 4) = *(const float4*)(xr + n0 + xcol4 * 4);
        } else {
          float* dst = xs + xrow * 16 + xcol4 * 4;
#pragma unroll
          for (int q = 0; q < 4; ++q) {
            int nn = n0 + xcol4 * 4 + q; if (nn > N_ - 1) nn = N_ - 1;
            dst[q] = xr[nn];
          }
        }
      }
#pragma unroll
      for (int sIdx = 0; sIdx < 12; ++sIdx) {
        int i4 = tid + sIdx * 192;
        int row = i4 / 48, col4 = i4 % 48;
        *(float4*)(ps + row * 192 + col4 * 4) =
            *(const float4*)(P + (size_t)(t0 + row) * 192 + col4 * 4);
      }
      __syncthreads();
#pragma unroll 4
      for (int kk = 0; kk < 48; ++kk) {
        float4 xv = *(const float4*)(xs + kk * 16 + nq * 4);
        float4 pv = *(const float4*)(ps + kk * 192 + c0);
        acc[0][0] = fmaf(pv.x, xv.x, acc[0][0]); acc[0][1] = fmaf(pv.x, xv.y, acc[0][1]);
        acc[0][2] = fmaf(pv.x, xv.z, acc[0][2]); acc[0][3] = fmaf(pv.x, xv.w, acc[0][3]);
        acc[1][0] = fmaf(pv.y, xv.x, acc[1][0]); acc[1][1] = fmaf(pv.y, xv.y, acc[1][1]);
        acc[1][2] = fmaf(pv.y, xv.z, acc[1][2]); acc[1][3] = fmaf(pv.y, xv.w, acc[1][3]);
        acc[2][0] = fmaf(pv.z, xv.x, acc[2][0]); acc[2][1] = fmaf(pv.z, xv.y, acc[2][1]);
        acc[2][2] = fmaf(pv.z, xv.z, acc[2][2]); acc[2][3] = fmaf(pv.z, xv.w, acc[2][3]);
        acc[3][0] = fmaf(pv.w, xv.x, acc[3][0]); acc[3][1] = fmaf(pv.w, xv.y, acc[3][1]);
        acc[3][2] = fmaf(pv.w, xv.z, acc[3][2]); acc[3][3] = fmaf(pv.w, xv.w, acc[3][3]);
      }
      __syncthreads();
    }
#pragma unroll
    for (int cc = 0; cc < 4; ++cc) {
      float4 v;
      v.x = acc[cc][0]; v.y = acc[cc][1]; v.z = acc[cc][2]; v.w = acc[cc][3];
      *(float4*)(ws + OFF_XPT + ((size_t)(b * 192 + c0 + cc)) * NR + n0 + nq * 4) = v;
    }
  } else if (id < 220) {
    // ---- top-6 / bottom-6 of xbar for batch b, then softmax weights
    __shared__ float s_sc[4][R_];
    __shared__ float s_scal[5];
    __shared__ float selv[12];
    __shared__ int seli[12];
    float* sx = smem;            // 864
    float* wkmax = smem + 864;   // 864
    float* wkmin = smem + 1728;  // 864
    int b = id - 216;
    if (tid < 16) {
      int r = tid & 7, which = tid >> 3;
      const float* W = which ? W2 : W1;
      float a = 0.f, bb = 0.f;
      for (int dd = 0; dd < D_; ++dd) {
        float w = W[dd * R_ + r];
        a += We[dd] * w; bb += be[dd] * w;
      }
      s_sc[which * 2][r] = a; s_sc[which * 2 + 1][r] = bb;
    }
    const float invT = 1.f / (float)T_;
    for (int i = tid; i < NB; i += 192) {
      float v = 0.f;
      if (i < N_) {
        const float* xp = ws + OFF_XBP + (size_t)(b * 6) * NB + i;
#pragma unroll
        for (int q = 0; q < 6; ++q) v += xp[q * NB];
        v *= invT;
      }
      sx[i] = v;
      wkmax[i] = (i < N_) ? v : -3.4e38f;
      wkmin[i] = (i < N_) ? v : 3.4e38f;
    }
    __syncthreads();
    if (tid == 0) {
      float s11 = 0.f, s12 = 0.f, s21 = 0.f, s22 = 0.f;
      for (int r = 0; r < R_; ++r) {
        s11 += s_sc[0][r] * s_sc[2][r];
        s12 += s_sc[0][r] * s_sc[3][r];
        s21 += s_sc[1][r] * s_sc[2][r];
        s22 += s_sc[1][r] * s_sc[3][r];
      }
      s_scal[0] = s11; s_scal[1] = s12; s_scal[2] = s21; s_scal[3] = s22;
      s_scal[4] = 1.f / (1.f + expf(-gate[0]));
    }
    if (tid < 64) {
      int lane = tid;
      for (int r = 0; r < K_; ++r) {
        float bv = -3.4e38f; int bi = 0;
        for (int i = lane; i < N_; i += 64) {
          float v = wkmax[i];
          if (v > bv) { bv = v; bi = i; }
        }
        for (int off = 32; off; off >>= 1) {
          float ov = __shfl_down(bv, off);
          int oi = __shfl_down(bi, off);
          if (ov > bv) { bv = ov; bi = oi; }
        }
        bv = __shfl(bv, 0); bi = __shfl(bi, 0);
        if (lane == 0) { selv[r] = bv; seli[r] = bi; wkmax[bi] = -3.4e38f; }
      }
    } else if (tid < 128) {
      int lane = tid - 64;
      for (int r = 0; r < K_; ++r) {
        float bv = 3.4e38f; int bi = 0;
        for (int i = lane; i < N_; i += 64) {
          float v = wkmin[i];
          if (v < bv) { bv = v; bi = i; }
        }
        for (int off = 32; off; off >>= 1) {
          float ov = __shfl_down(bv, off);
          int oi = __shfl_down(bi, off);
          if (ov < bv) { bv = ov; bi = oi; }
        }
        bv = __shfl(bv, 0); bi = __shfl(bi, 0);
        if (lane == 0) { selv[6 + r] = bv; seli[6 + r] = bi; wkmin[bi] = 3.4e38f; }
      }
    }
    __syncthreads();
    float s11 = s_scal[0], s12 = s_scal[1], s21 = s_scal[2], s22 = s_scal[3];
    float g = s_scal[4];
    const float rsq = 0.3535533906f;
    for (int n = tid; n < N_; n += 192) {
      float xn = sx[n];
      float alpha = (xn * s11 + s21) * rsq;
      float beta  = (xn * s12 + s22) * rsq;
      int base = (alpha >= 0.f) ? 0 : 6;
      float l[K_]; float mx = -3.4e38f;
#pragma unroll
      for (int j = 0; j < K_; ++j) { l[j] = alpha * selv[base + j] + beta; mx = fmaxf(mx, l[j]); }
      float e[K_]; float ss = 0.f;
#pragma unroll
      for (int j = 0; j < K_; ++j) { e[j] = expf(l[j] - mx); ss += e[j]; }
      float sc = g / ss;
#pragma unroll
      for (int j = 0; j < K_; ++j) {
        ws[OFF_WGT + j * (4 * NB) + b * NB + n] = e[j] * sc;
        ((int*)(ws + OFF_IDX))[j * (4 * NB) + b * NB + n] = seli[base + j];
      }
    }
  } else {
    // ---- PC/PA partial column reduce: block q sums 84 t's
    int q = id - 220;
    int c = tid;
    float s = 0.f;
#pragma unroll 12
    for (int t = q * 84; t < q * 84 + 84; ++t) s += ws[OFF_PCP + t * 192 + c];
    ws[OFF_PCQ + q * 192 + c] = s;
  }
}

// ---------------- Phase C: fused mix1 + on-the-fly GCN + assembly.
// grid(4,384) x 256. blockIdx.y = c = b*96+p.
__global__ void kF_final(const float* __restrict__ A, const float* __restrict__ bhead,
                         const float* __restrict__ ggcn, const float* __restrict__ ws,
                         float* __restrict__ out) {
  int c = blockIdx.y;
  int n = blockIdx.x * 256 + threadIdx.x;
  if (n >= N_) return;
  int b = c / P_, p = c % P_;
  const float* Xp1 = ws + OFF_XPT + ((size_t)(b * 192 + p)) * NR;
  const float* Xp2 = ws + OFF_XPT + ((size_t)(b * 192 + P_ + p)) * NR;
  const float* WGTb = ws + OFF_WGT + b * NB;
  const int* IDXb = (const int*)(ws + OFF_IDX) + b * NB;
  float gg = ggcn[0];
  float PCp = 0.f, PAp = 0.f;
#pragma unroll
  for (int q = 0; q < 4; ++q) {
    PCp += ws[OFF_PCQ + q * 192 + p];
    PAp += ws[OFF_PCQ + q * 192 + 96 + p];
  }
  float acc1 = Xp1[n];
#pragma unroll
  for (int j = 0; j < K_; ++j)
    acc1 += WGTb[j * (4 * NB) + n] * Xp1[IDXb[j * (4 * NB) + n]];
  int cnt = ((const int*)(ws + OFF_CNT))[n];
  float S = 0.f;
  if (cnt >= 0) {
    const float* vv = ws + OFF_CSRV;
    const int* ii = (const int*)(ws + OFF_CSRI);
    for (int jj = 0; jj < cnt; ++jj) {
      float a = vv[jj * NB + n];
      int m = ii[jj * NB + n];
      float mix2 = Xp2[m];
#pragma unroll
      for (int j = 0; j < K_; ++j)
        mix2 += WGTb[j * (4 * NB) + m] * Xp2[IDXb[j * (4 * NB) + m]];
      S += a * ws[OFF_DINV + m] * (mix2 + PAp);
    }
  } else {
    const float* ar = A + (size_t)n * N_;
    for (int m = 0; m < N_; ++m) {
      float a = ar[m];
      if (a != 0.f) {
        float mix2 = Xp2[m];
#pragma unroll
        for (int j = 0; j < K_; ++j)
          mix2 += WGTb[j * (4 * NB) + m] * Xp2[IDXb[j * (4 * NB) + m]];
        S += a * ws[OFF_DINV + m] * (mix2 + PAp);
      }
    }
  }
  out[(size_t)c * N_ + n] = acc1 + gg * ws[OFF_DINV + n] * S + PCp + bhead[p];
}

extern "C" void kernel_launch(void* const* d_in, const int* in_sizes, int n_in,
                              void* d_out, int out_size, void* d_ws, size_t ws_size,
                              hipStream_t stream) {
  const float* x     = (const float*)d_in[0];
  const float* We    = (const float*)d_in[1];
  const float* be    = (const float*)d_in[2];
  const float* W1    = (const float*)d_in[3];
  const float* W2    = (const float*)d_in[4];
  const float* gate  = (const float*)d_in[5];
  const float* A     = (const float*)d_in[6];
  const float* Wgcn  = (const float*)d_in[7];
  const float* ggcn  = (const float*)d_in[8];
  const float* Whead = (const float*)d_in[9];
  const float* bhead = (const float*)d_in[10];
  float* ws = (float*)d_ws;
  float* out = (float*)d_out;

  kA_prep<<<960, 192, 0, stream>>>(x, Whead, A, We, be, gate, Wgcn, ws);
  kM_mid<<<224, 192, 0, stream>>>(x, W1, W2, We, be, gate, ws);
  kF_final<<<dim3(4, 384), 256, 0, stream>>>(A, bhead, ggcn, ws, out);
}